// Round 13
// baseline (167.664 us; speedup 1.0000x reference)
//
#include <hip/hip_runtime.h>
#include <hip/hip_bf16.h>
#include <hip/hip_fp16.h>

#define N_NODES 50000
#define N_EDGES 20000
#define EDGE_K  32
#define CH      256
#define N_INC   (N_EDGES * EDGE_K)   // 640000 incidences
#define ELL_CAP 64                   // max node degree capacity (Poisson(12.8))
#define NSLICE  8                    // channel slices == XCD count
#define SCH     32                   // channels per slice (32 x 2B = 64B rows)
#define ZROW    N_EDGES              // dedicated all-zeros yb row (clamp target)

typedef __attribute__((ext_vector_type(4))) float f32x4;
typedef __attribute__((ext_vector_type(8))) _Float16 f16x8;

static __device__ __forceinline__ __half2 u2h2(unsigned int u) {
    __half2 h; __builtin_memcpy(&h, &u, 4); return h;
}
static __device__ __forceinline__ unsigned int h22u(__half2 h) {
    unsigned int u; __builtin_memcpy(&u, &h, 4); return u;
}
static __device__ __forceinline__ unsigned int pk2h(float a, float b) {
    return h22u(__halves2half2(__float2half_rn(a), __float2half_rn(b)));
}

// async global->LDS, 16B per lane: dest = ldsbase + lane*16 (linear), src per-lane.
static __device__ __forceinline__ void gll16(const void* g, void* l) {
    __builtin_amdgcn_global_load_lds(
        (const __attribute__((address_space(1))) void*)g,
        (__attribute__((address_space(3))) void*)l,
        16, 0, 0);
}

// Fused prep: [0,CONV) x->fp16 sliced [8][N][32] | [+CH) W^T fp16 | [last] yb zero-row
#define CONV_BLOCKS (N_NODES * CH / 8 / 256)           // 6250
__global__ void prep_kernel(const float* __restrict__ x, unsigned short* __restrict__ xb,
                            const float* __restrict__ w, unsigned short* __restrict__ wt,
                            unsigned short* __restrict__ yb) {
    int b = blockIdx.x;
    if (b < CONV_BLOCKS) {
        int i = b * 256 + threadIdx.x;        // one per 8 channels
        int n = i >> 5, sub = i & 31;
        int g = sub >> 2, cp = (sub & 3) * 8;
        const float* src = x + (size_t)n * CH + sub * 8;
        f32x4 v0 = *reinterpret_cast<const f32x4*>(src);
        f32x4 v1 = *reinterpret_cast<const f32x4*>(src + 4);
        uint4 u;
        u.x = pk2h(v0.x, v0.y);
        u.y = pk2h(v0.z, v0.w);
        u.z = pk2h(v1.x, v1.y);
        u.w = pk2h(v1.z, v1.w);
        *reinterpret_cast<uint4*>(xb + ((size_t)g * N_NODES + n) * SCH + cp) = u;
    } else if (b < CONV_BLOCKS + CH) {
        int n = b - CONV_BLOCKS;
        int k = threadIdx.x;
        __half h = __float2half_rn(w[k * CH + n]);
        wt[n * CH + k] = *reinterpret_cast<unsigned short*>(&h);
    } else {
        // zero the dedicated yb zero-row for each slice (8 x 32 halves = 256)
        int g = threadIdx.x >> 5, c = threadIdx.x & 31;
        yb[((size_t)g * (N_EDGES + 1) + ZROW) * SCH + c] = 0;
    }
}

// Fused: ELL-fill (head, XCD-partitioned, batched index loads) + gll-gather (tail).
// Gather wave = 4 edges x slice g=blockIdx&7 (L2-resident 3.2MB slice): 8 async
// global_load_lds (16 rows each, swizzled source), vmcnt(0), LDS reduce.
#define FILL_GROUPS   8
#define NODES_PER_GRP (N_NODES / FILL_GROUPS)
#define FILL_WIN      1280
#define FILL_BLOCKS   ((N_INC / FILL_WIN) * FILL_GROUPS) // 500*8 = 4000
#define GATHER_BLOCKS ((N_EDGES / 16) * NSLICE)          // 10000
__global__ __launch_bounds__(256) void gather_fill_kernel(
        const unsigned short* __restrict__ xb, const int* __restrict__ he,
        unsigned short* __restrict__ es, int* __restrict__ deg,
        unsigned short* __restrict__ ell) {
    __shared__ __align__(16) unsigned short glds[16384];   // 32KB: 4 waves x 8KB
    int b = blockIdx.x;
    if (b < FILL_BLOCKS) {
        int g  = b & 7;                       // node-range group == XCD heuristic
        int wn = b >> 3;
        int lo = g * NODES_PER_GRP, hi = lo + NODES_PER_GRP;
        int i0 = wn * FILL_WIN + threadIdx.x;
        // batch the 5 index loads (independent), then process
        int n0 = he[i0];
        int n1 = he[i0 + 256];
        int n2 = he[i0 + 512];
        int n3 = he[i0 + 768];
        int n4 = he[i0 + 1024];
        if (n0 >= lo && n0 < hi) { int s = atomicAdd(&deg[n0], 1); if (s < ELL_CAP) ell[(size_t)n0 * ELL_CAP + s] = (unsigned short)(i0 >> 5); }
        if (n1 >= lo && n1 < hi) { int s = atomicAdd(&deg[n1], 1); if (s < ELL_CAP) ell[(size_t)n1 * ELL_CAP + s] = (unsigned short)((i0 + 256) >> 5); }
        if (n2 >= lo && n2 < hi) { int s = atomicAdd(&deg[n2], 1); if (s < ELL_CAP) ell[(size_t)n2 * ELL_CAP + s] = (unsigned short)((i0 + 512) >> 5); }
        if (n3 >= lo && n3 < hi) { int s = atomicAdd(&deg[n3], 1); if (s < ELL_CAP) ell[(size_t)n3 * ELL_CAP + s] = (unsigned short)((i0 + 768) >> 5); }
        if (n4 >= lo && n4 < hi) { int s = atomicAdd(&deg[n4], 1); if (s < ELL_CAP) ell[(size_t)n4 * ELL_CAP + s] = (unsigned short)((i0 + 1024) >> 5); }
        return;
    }
    int gb  = b - FILL_BLOCKS;
    int g   = gb & 7;                 // slice == XCD (round-robin heuristic)
    int grp = gb >> 3;
    int w = threadIdx.x >> 6, lane = threadIdx.x & 63;
    int ebase = grp * 16 + w * 4;     // this wave's 4 edges
    const int* hp = he + (size_t)ebase * EDGE_K;
    int el = lane >> 4, s = lane & 15;
    int mA = hp[el * 32 + s];         // edge el, node slots 0..15
    int mB = hp[el * 32 + 16 + s];    // edge el, node slots 16..31
    const unsigned short* xg = xb + (size_t)g * N_NODES * SCH;
    unsigned short* my = &glds[w * 4096];     // 8KB region (ushort idx)
    int rsel = lane >> 2;             // row 0..15 within a 16-row stage
    int sub  = (lane + rsel) & 3;     // source swizzle: slot holds chunk (slot+row)&3
    // issue all 8 async loads (16 rows x 64B each), zero VGPR cost
#pragma unroll
    for (int t = 0; t < 4; ++t) {
        int vA = __shfl(mA, t * 16 + rsel, 64);
        int vB = __shfl(mB, t * 16 + rsel, 64);
        gll16(xg + (size_t)vA * SCH + sub * 8, my + t * 1024);
        gll16(xg + (size_t)vB * SCH + sub * 8, my + t * 1024 + 512);
    }
    asm volatile("s_waitcnt vmcnt(0)" ::: "memory");
    __builtin_amdgcn_sched_barrier(0);
    // reduce 32 rows -> 1 per edge; roles (t2=edge, rr, chunk)
    int t2 = lane >> 4, rr = (lane >> 2) & 3, chunk = lane & 3;
    int rsub = (chunk - rr) & 3;      // un-swizzle: (chunk - r)&3, r==rr (mod 4)
    const unsigned short* rb = my + t2 * 1024 + rr * 32 + rsub * 8;
    __half2 a0 = u2h2(0u), a1 = u2h2(0u), a2 = u2h2(0u), a3 = u2h2(0u);
#pragma unroll
    for (int i = 0; i < 8; ++i) {     // rows r = rr + 4i
        uint4 d = *reinterpret_cast<const uint4*>(rb + i * 128);
        a0 = __hadd2(a0, u2h2(d.x)); a1 = __hadd2(a1, u2h2(d.y));
        a2 = __hadd2(a2, u2h2(d.z)); a3 = __hadd2(a3, u2h2(d.w));
    }
    a0 = __hadd2(a0, u2h2(__shfl_xor(h22u(a0), 4, 64)));
    a1 = __hadd2(a1, u2h2(__shfl_xor(h22u(a1), 4, 64)));
    a2 = __hadd2(a2, u2h2(__shfl_xor(h22u(a2), 4, 64)));
    a3 = __hadd2(a3, u2h2(__shfl_xor(h22u(a3), 4, 64)));
    a0 = __hadd2(a0, u2h2(__shfl_xor(h22u(a0), 8, 64)));
    a1 = __hadd2(a1, u2h2(__shfl_xor(h22u(a1), 8, 64)));
    a2 = __hadd2(a2, u2h2(__shfl_xor(h22u(a2), 8, 64)));
    a3 = __hadd2(a3, u2h2(__shfl_xor(h22u(a3), 8, 64)));
    if ((lane & 12) == 0) {           // rr==0 lanes: (edge t2, chunk)
        uint4 u;
        u.x = h22u(a0); u.y = h22u(a1); u.z = h22u(a2); u.w = h22u(a3);
        *reinterpret_cast<uint4*>(es + (size_t)(ebase + t2) * CH + g * SCH + chunk * 8) = u;
    }
}

// Y = es(fp16) @ W(fp16) via mfma_f32_16x16x32_f16; yb stored SLICED [8][E+1][32]
__global__ __launch_bounds__(256) void gemm_kernel(const unsigned short* __restrict__ es,
                                                   const unsigned short* __restrict__ wt,
                                                   unsigned short* __restrict__ yb) {
    int wid  = threadIdx.x >> 6;
    int lane = threadIdx.x & 63;
    int m0   = blockIdx.x * 64 + wid * 16;
    if (m0 >= N_EDGES) return;
    int lr = lane & 15;
    int lg = lane >> 4;

    f32x4 acc[16] = {};
    const unsigned short* arow = es + (size_t)(m0 + lr) * CH + lg * 8;
#pragma unroll
    for (int kk = 0; kk < CH; kk += 32) {
        f16x8 a = *reinterpret_cast<const f16x8*>(arow + kk);
#pragma unroll
        for (int nt = 0; nt < 16; ++nt) {
            f16x8 bb = *reinterpret_cast<const f16x8*>(
                wt + (size_t)(nt * 16 + lr) * CH + kk + lg * 8);
            acc[nt] = __builtin_amdgcn_mfma_f32_16x16x32_f16(a, bb, acc[nt], 0, 0, 0);
        }
    }
    // D layout: col = lane&15, row = (lane>>4)*4 + r  -> sliced write
#pragma unroll
    for (int nt = 0; nt < 16; ++nt) {
#pragma unroll
        for (int r = 0; r < 4; ++r) {
            int row = m0 + lg * 4 + r;
            __half h = __float2half_rn(acc[nt][r]);
            yb[((size_t)(nt >> 1) * (N_EDGES + 1) + row) * SCH + (nt & 1) * 16 + lr] =
                *reinterpret_cast<unsigned short*>(&h);
        }
    }
}

// out[n][g*32..] = relu( sum_j yb[g][ell[n][j]][:] ) -- gll-staged, ZROW-clamped,
// rare (deg>32) tail via direct loads. Wave = 4 nodes x slice.
#define AP_BLOCKS ((N_NODES / 16) * NSLICE)    // 25000
__global__ __launch_bounds__(256) void apply_kernel(
        const unsigned short* __restrict__ yb, const int* __restrict__ deg,
        const unsigned short* __restrict__ ell, float* __restrict__ out) {
    __shared__ __align__(16) unsigned short alds[16384];   // 32KB
    int b = blockIdx.x;
    int g = b & 7;                    // slice == XCD
    int w = threadIdx.x >> 6, lane = threadIdx.x & 63;
    int nb = (b >> 3) * 16 + w * 4;   // this wave's 4 nodes
    int el = lane >> 4, s = lane & 15;
    int node_own = nb + el;
    int d_own = deg[node_own];
    if (d_own > ELL_CAP) d_own = ELL_CAP;
    const unsigned short* er = ell + (size_t)node_own * ELL_CAP;
    int m0 = er[s], m1 = er[16 + s];
    int dmax = d_own;
    dmax = max(dmax, __shfl_xor(dmax, 16, 64));
    dmax = max(dmax, __shfl_xor(dmax, 32, 64));   // wave-uniform
    const unsigned short* yg = yb + (size_t)g * (N_EDGES + 1) * SCH;
    unsigned short* my = &alds[w * 4096];
    int rsel = lane >> 2;
    int sub  = (lane + rsel) & 3;
#pragma unroll
    for (int t = 0; t < 4; ++t) {
        int dt = __shfl(d_own, t * 16, 64);
        int vA = __shfl(m0, t * 16 + rsel, 64); vA = (rsel < dt) ? vA : ZROW;
        int vB = __shfl(m1, t * 16 + rsel, 64); vB = (16 + rsel < dt) ? vB : ZROW;
        gll16(yg + (size_t)vA * SCH + sub * 8, my + t * 1024);
        gll16(yg + (size_t)vB * SCH + sub * 8, my + t * 1024 + 512);
    }
    asm volatile("s_waitcnt vmcnt(0)" ::: "memory");
    __builtin_amdgcn_sched_barrier(0);
    int t2 = lane >> 4, rr = (lane >> 2) & 3, chunk = lane & 3;
    int rsub = (chunk - rr) & 3;
    const unsigned short* rb = my + t2 * 1024 + rr * 32 + rsub * 8;
    __half2 a0 = u2h2(0u), a1 = u2h2(0u), a2 = u2h2(0u), a3 = u2h2(0u);
#pragma unroll
    for (int i = 0; i < 8; ++i) {
        uint4 d = *reinterpret_cast<const uint4*>(rb + i * 128);
        a0 = __hadd2(a0, u2h2(d.x)); a1 = __hadd2(a1, u2h2(d.y));
        a2 = __hadd2(a2, u2h2(d.z)); a3 = __hadd2(a3, u2h2(d.w));
    }
    if (dmax > 32) {                  // rare tail: slots 32..63, direct loads
        int m2 = er[32 + s], m3 = er[48 + s];
        int dt2 = __shfl(d_own, t2 * 16, 64);
#pragma unroll
        for (int i = 0; i < 8; ++i) {
            int sl = rr + 4 * i;      // 0..31 -> slot 32+sl
            int v = __shfl((i < 4) ? m2 : m3, t2 * 16 + (sl & 15), 64);
            v = (32 + sl < dt2) ? v : ZROW;
            uint4 d = *reinterpret_cast<const uint4*>(yg + (size_t)v * SCH + chunk * 8);
            a0 = __hadd2(a0, u2h2(d.x)); a1 = __hadd2(a1, u2h2(d.y));
            a2 = __hadd2(a2, u2h2(d.z)); a3 = __hadd2(a3, u2h2(d.w));
        }
    }
    a0 = __hadd2(a0, u2h2(__shfl_xor(h22u(a0), 4, 64)));
    a1 = __hadd2(a1, u2h2(__shfl_xor(h22u(a1), 4, 64)));
    a2 = __hadd2(a2, u2h2(__shfl_xor(h22u(a2), 4, 64)));
    a3 = __hadd2(a3, u2h2(__shfl_xor(h22u(a3), 4, 64)));
    a0 = __hadd2(a0, u2h2(__shfl_xor(h22u(a0), 8, 64)));
    a1 = __hadd2(a1, u2h2(__shfl_xor(h22u(a1), 8, 64)));
    a2 = __hadd2(a2, u2h2(__shfl_xor(h22u(a2), 8, 64)));
    a3 = __hadd2(a3, u2h2(__shfl_xor(h22u(a3), 8, 64)));
    if ((lane & 12) == 0) {           // rr==0 lanes: (node t2, chunk)
        int node = nb + t2;
        float2 f0 = __half22float2(a0);
        float2 f1 = __half22float2(a1);
        float2 f2 = __half22float2(a2);
        float2 f3 = __half22float2(a3);
        f32x4 r0, r1;
        r0.x = fmaxf(f0.x, 0.f); r0.y = fmaxf(f0.y, 0.f);
        r0.z = fmaxf(f1.x, 0.f); r0.w = fmaxf(f1.y, 0.f);
        r1.x = fmaxf(f2.x, 0.f); r1.y = fmaxf(f2.y, 0.f);
        r1.z = fmaxf(f3.x, 0.f); r1.w = fmaxf(f3.y, 0.f);
        float* dst = out + (size_t)node * CH + g * SCH + chunk * 8;
        *reinterpret_cast<f32x4*>(dst)     = r0;
        *reinterpret_cast<f32x4*>(dst + 4) = r1;
    }
}

extern "C" void kernel_launch(void* const* d_in, const int* in_sizes, int n_in,
                              void* d_out, int out_size, void* d_ws, size_t ws_size,
                              hipStream_t stream) {
    const float* x  = (const float*)d_in[0];
    const int*   he = (const int*)d_in[1];
    const float* w  = (const float*)d_in[2];
    float* out = (float*)d_out;

    // workspace layout
    char* ws = (char*)d_ws;
    unsigned short* wt  = (unsigned short*)ws;                        // 131072 B
    unsigned short* es  = (unsigned short*)(ws + 131072);             // 10240000 B
    unsigned short* yb  = (unsigned short*)(ws + 10371072);           // 8*20001*32*2 = 10240512 B
    int* deg = (int*)(ws + 20611584);                                 // 200000 B
    unsigned short* ell = (unsigned short*)(ws + 20811584);           // 6400000 B

    // xb (fp16 x, sliced [8][N][32], 25.6 MB) lives inside d_out (51.2 MB f32)
    unsigned short* xb = (unsigned short*)d_out;

    hipMemsetAsync(deg, 0, (size_t)N_NODES * 4, stream);

    prep_kernel<<<CONV_BLOCKS + CH + 1, 256, 0, stream>>>(x, xb, w, wt, yb);

    gather_fill_kernel<<<FILL_BLOCKS + GATHER_BLOCKS, 256, 0, stream>>>(xb, he, es, deg, ell);

    {
        int blocks = (N_EDGES + 63) / 64;
        gemm_kernel<<<blocks, 256, 0, stream>>>(es, wt, yb);
    }

    apply_kernel<<<AP_BLOCKS, 256, 0, stream>>>(yb, deg, ell, out);
}